// Round 3
// baseline (1886.165 us; speedup 1.0000x reference)
//
#include <hip/hip_runtime.h>
#include <math.h>

#define B_ROWS 32768
#define D_DIM  512
#define K_EMB  8192

#define BMT 128
#define BNT 128
#define KSPLIT1 4
#define KRANGE1 (K_EMB / KSPLIT1)   // 2048
#define RSPLIT 8
#define KRANGE_R (K_EMB / RSPLIT)   // 1024
#define EPS 0.10f

typedef __attribute__((ext_vector_type(4))) float f32x4;
typedef __attribute__((ext_vector_type(8))) short bf16x8;

#define GLL16(gp, lp)                                                          \
  __builtin_amdgcn_global_load_lds(                                            \
      (const __attribute__((address_space(1))) void*)(gp),                     \
      (__attribute__((address_space(3))) void*)(lp), 16, 0, 0)

// ---------------------------------------------------------------------------
// fp32 -> bf16 hi + residual lo (RNE), fused with row squared-norm.
// One wave per row (64 lanes x 8 floats = 512).
// ---------------------------------------------------------------------------
__device__ __forceinline__ unsigned bf_rne(float x) {
  unsigned u = __float_as_uint(x);
  return (u + 0x7fffu + ((u >> 16) & 1u)) >> 16;
}

__global__ __launch_bounds__(256) void prep_kernel(
    const float* __restrict__ X, short* __restrict__ hi,
    short* __restrict__ lo, float* __restrict__ sq, int nrows) {
  const int wave = threadIdx.x >> 6;
  const int lane = threadIdx.x & 63;
  const int row = blockIdx.x * 4 + wave;
  if (row >= nrows) return;
  const float* xr = X + (size_t)row * D_DIM;
  float4 x0 = ((const float4*)xr)[lane * 2];
  float4 x1 = ((const float4*)xr)[lane * 2 + 1];
  float xs[8] = {x0.x, x0.y, x0.z, x0.w, x1.x, x1.y, x1.z, x1.w};
  union { short s[8]; int4 v; } H, L;
  float ssum = 0.f;
  #pragma unroll
  for (int j = 0; j < 8; ++j) {
    unsigned rh = bf_rne(xs[j]);
    H.s[j] = (short)rh;
    float h = __uint_as_float(rh << 16);
    L.s[j] = (short)bf_rne(xs[j] - h);
    ssum += xs[j] * xs[j];
  }
  *(int4*)(hi + (size_t)row * D_DIM + lane * 8) = H.v;
  *(int4*)(lo + (size_t)row * D_DIM + lane * 8) = L.v;
  #pragma unroll
  for (int o = 32; o > 0; o >>= 1) ssum += __shfl_xor(ssum, o, 64);
  if (lane == 0) sq[row] = ssum;
}

// ---------------------------------------------------------------------------
// Stage 1: hi*hi approximate distance GEMM with per-row TOP-2 (val1,idx1,val2).
// Proxy distance = wsq[c] - 2*dot  (zz[r] is row-constant: ordering unchanged).
// 128x128 tile, KSPLIT1=4. LDS: 16 KB tiles overlaid by 48 KB reduction union.
// ---------------------------------------------------------------------------
__global__ __launch_bounds__(256, 3) void stage1_kernel(
    const short* __restrict__ zhi, const short* __restrict__ whi,
    const float* __restrict__ wsq, float* __restrict__ cv1,
    int* __restrict__ ci1, float* __restrict__ cv2) {
  __shared__ char smem[49152];
  short* Ah = (short*)smem;             // 8 KB
  short* Bh = (short*)(smem + 8192);    // 8 KB
  float* rv1 = (float*)smem;            // 16 KB (post-loop overlay)
  int*   ri1 = (int*)(smem + 16384);    // 16 KB
  float* rv2 = (float*)(smem + 32768);  // 16 KB

  const int tid = threadIdx.x;
  const int lane = tid & 63;
  const int wave = tid >> 6;
  const int wm = wave >> 1, wn = wave & 1;
  const int l15 = lane & 15, l4 = lane >> 4;

  const int bx = blockIdx.x;
  const int row0 = (bx >> 2) * BMT;
  const int ksp = bx & 3;
  const int k0 = ksp * KRANGE1;

  const int r0s = tid & 127;   // staging row for both slots
  const int kc0 = tid >> 7;    // k-chunk of slot tid (0..1)
  const int kc1 = kc0 + 2;     // k-chunk of slot tid+256 (2..3)

  float v1[16], v2[16];
  int   i1[16];
  #pragma unroll
  for (int s = 0; s < 16; ++s) { v1[s] = INFINITY; v2[s] = INFINITY; i1[s] = 0x7fffffff; }

  for (int kt = 0; kt < KRANGE1; kt += BNT) {
    f32x4 acc[4][4];
    #pragma unroll
    for (int rb = 0; rb < 4; ++rb)
      #pragma unroll
      for (int cb = 0; cb < 4; ++cb) acc[rb][cb] = (f32x4)0.f;

    for (int d0 = 0; d0 < D_DIM; d0 += 32) {
      const size_t ga0 = (size_t)(row0 + r0s) * D_DIM + d0 + kc0 * 8;
      const size_t ga1 = (size_t)(row0 + r0s) * D_DIM + d0 + kc1 * 8;
      const size_t gb0 = (size_t)(k0 + kt + r0s) * D_DIM + d0 + kc0 * 8;
      const size_t gb1 = (size_t)(k0 + kt + r0s) * D_DIM + d0 + kc1 * 8;
      GLL16(zhi + ga0, Ah + (size_t)tid * 8);
      GLL16(zhi + ga1, Ah + (size_t)(tid + 256) * 8);
      GLL16(whi + gb0, Bh + (size_t)tid * 8);
      GLL16(whi + gb1, Bh + (size_t)(tid + 256) * 8);
      __syncthreads();

      bf16x8 ah[4], bh[4];
      #pragma unroll
      for (int rb = 0; rb < 4; ++rb) {
        const int m = wm * 64 + rb * 16 + l15;
        ah[rb] = *(const bf16x8*)&Ah[(l4 * 128 + m) * 8];
      }
      #pragma unroll
      for (int cb = 0; cb < 4; ++cb) {
        const int n = wn * 64 + cb * 16 + l15;
        bh[cb] = *(const bf16x8*)&Bh[(l4 * 128 + n) * 8];
      }
      #pragma unroll
      for (int rb = 0; rb < 4; ++rb)
        #pragma unroll
        for (int cb = 0; cb < 4; ++cb)
          acc[rb][cb] = __builtin_amdgcn_mfma_f32_16x16x32_bf16(
              ah[rb], bh[cb], acc[rb][cb], 0, 0, 0);
      __syncthreads();
    }

    #pragma unroll
    for (int cb = 0; cb < 4; ++cb) {
      const int col = k0 + kt + wn * 64 + cb * 16 + l15;
      const float wv = wsq[col];
      #pragma unroll
      for (int rb = 0; rb < 4; ++rb) {
        f32x4 a = acc[rb][cb];
        #pragma unroll
        for (int rg = 0; rg < 4; ++rg) {
          const float dist = wv - 2.0f * a[rg];
          const int s = rb * 4 + rg;
          if (dist < v1[s] || (dist == v1[s] && col < i1[s])) {
            v2[s] = v1[s]; v1[s] = dist; i1[s] = col;
          } else {
            v2[s] = fminf(v2[s], dist);
          }
        }
      }
    }
  }

  // overlay reduction arrays on the (now dead) tile buffers
  #pragma unroll
  for (int rb = 0; rb < 4; ++rb)
    #pragma unroll
    for (int rg = 0; rg < 4; ++rg) {
      const int s = rb * 4 + rg;
      const int R = wm * 64 + rb * 16 + l4 * 4 + rg;
      const int c = wn * 16 + l15;
      rv1[R * 32 + c] = v1[s];
      ri1[R * 32 + c] = i1[s];
      rv2[R * 32 + c] = v2[s];
    }
  __syncthreads();

  if (tid < BMT) {
    float V1 = INFINITY, V2 = INFINITY;
    int I1 = 0x7fffffff;
    #pragma unroll
    for (int t = 0; t < 32; ++t) {
      const float a1 = rv1[tid * 32 + t];
      const int ai = ri1[tid * 32 + t];
      const float a2 = rv2[tid * 32 + t];
      if (a1 < V1 || (a1 == V1 && ai < I1)) {
        V2 = fminf(V1, a2); V1 = a1; I1 = ai;
      } else {
        V2 = fminf(V2, a1);
      }
    }
    const size_t o = (size_t)ksp * B_ROWS + row0 + tid;
    cv1[o] = V1; ci1[o] = I1; cv2[o] = V2;
  }
}

// ---------------------------------------------------------------------------
// Merge the 4 split-K top-2 candidates per row; commit unambiguous rows,
// compact ambiguous rows into a refine list.
// ---------------------------------------------------------------------------
__global__ __launch_bounds__(256) void merge_flag_kernel(
    const float* __restrict__ cv1, const int* __restrict__ ci1,
    const float* __restrict__ cv2, int* __restrict__ idx,
    float* __restrict__ out_idx_f, int* __restrict__ hist,
    unsigned long long* __restrict__ packed, int* __restrict__ cnt,
    int* __restrict__ list) {
  const int row = blockIdx.x * 256 + threadIdx.x;
  float V1 = INFINITY, V2 = INFINITY;
  int I1 = 0x7fffffff;
  #pragma unroll
  for (int sp = 0; sp < KSPLIT1; ++sp) {
    const size_t o = (size_t)sp * B_ROWS + row;
    const float a1 = cv1[o];
    const int ai = ci1[o];
    const float a2 = cv2[o];
    if (a1 < V1 || (a1 == V1 && ai < I1)) {
      V2 = fminf(V1, a2); V1 = a1; I1 = ai;
    } else {
      V2 = fminf(V2, a1);
    }
  }
  if (V2 - V1 >= EPS) {
    idx[row] = I1;
    out_idx_f[row] = (float)I1;
    atomicAdd(&hist[I1], 1);
  } else {
    packed[row] = 0xffffffffffffffffULL;
    const int p = atomicAdd(cnt, 1);
    list[p] = row;
  }
}

// ---------------------------------------------------------------------------
// Refine: exact 3-pass (hi*hi + hi*lo + lo*hi) distance argmin over ALL codes
// for flagged rows only (gathered via list). Split-K=8, merged via packed
// atomicMin (positive fp32 bits || idx -> exact value-then-lowest-idx order).
// Grid is static worst-case; blocks beyond the flagged count exit early.
// ---------------------------------------------------------------------------
__global__ __launch_bounds__(256, 2) void refine_kernel(
    const short* __restrict__ zhi, const short* __restrict__ zlo,
    const short* __restrict__ whi, const short* __restrict__ wlo,
    const float* __restrict__ zz, const float* __restrict__ wsq,
    const int* __restrict__ cnt, const int* __restrict__ list,
    unsigned long long* __restrict__ packed) {
  __shared__ char smem[32768];
  short* Ah = (short*)smem;
  short* Al = (short*)(smem + 8192);
  short* Bh = (short*)(smem + 16384);
  short* Bl = (short*)(smem + 24576);
  float* rv = (float*)smem;             // post-loop overlay
  int*   ri = (int*)(smem + 16384);

  const int n = *cnt;
  const int bx = blockIdx.x;
  const int rt = bx >> 3;
  const int ks = bx & 7;
  if (rt * BMT >= n) return;
  const int k0 = ks * KRANGE_R;

  const int tid = threadIdx.x;
  const int lane = tid & 63;
  const int wave = tid >> 6;
  const int wm = wave >> 1, wn = wave & 1;
  const int l15 = lane & 15, l4 = lane >> 4;

  const int r0s = tid & 127;
  const int kc0 = tid >> 7;
  const int kc1 = kc0 + 2;
  const int rowg = list[min(rt * BMT + r0s, n - 1)];

  float zzr[16];
  #pragma unroll
  for (int rb = 0; rb < 4; ++rb)
    #pragma unroll
    for (int rg = 0; rg < 4; ++rg) {
      const int m = wm * 64 + rb * 16 + l4 * 4 + rg;
      zzr[rb * 4 + rg] = zz[list[min(rt * BMT + m, n - 1)]];
    }

  float best[16];
  int   bidx[16];
  #pragma unroll
  for (int s = 0; s < 16; ++s) { best[s] = INFINITY; bidx[s] = 0x7fffffff; }

  for (int kt = 0; kt < KRANGE_R; kt += BNT) {
    f32x4 acc[4][4];
    #pragma unroll
    for (int rb = 0; rb < 4; ++rb)
      #pragma unroll
      for (int cb = 0; cb < 4; ++cb) acc[rb][cb] = (f32x4)0.f;

    for (int d0 = 0; d0 < D_DIM; d0 += 32) {
      const size_t ga0 = (size_t)rowg * D_DIM + d0 + kc0 * 8;
      const size_t ga1 = (size_t)rowg * D_DIM + d0 + kc1 * 8;
      const size_t gb0 = (size_t)(k0 + kt + r0s) * D_DIM + d0 + kc0 * 8;
      const size_t gb1 = (size_t)(k0 + kt + r0s) * D_DIM + d0 + kc1 * 8;
      GLL16(zhi + ga0, Ah + (size_t)tid * 8);
      GLL16(zhi + ga1, Ah + (size_t)(tid + 256) * 8);
      GLL16(zlo + ga0, Al + (size_t)tid * 8);
      GLL16(zlo + ga1, Al + (size_t)(tid + 256) * 8);
      GLL16(whi + gb0, Bh + (size_t)tid * 8);
      GLL16(whi + gb1, Bh + (size_t)(tid + 256) * 8);
      GLL16(wlo + gb0, Bl + (size_t)tid * 8);
      GLL16(wlo + gb1, Bl + (size_t)(tid + 256) * 8);
      __syncthreads();

      bf16x8 ah[4], al[4], bh[4], bl[4];
      #pragma unroll
      for (int rb = 0; rb < 4; ++rb) {
        const int m = wm * 64 + rb * 16 + l15;
        ah[rb] = *(const bf16x8*)&Ah[(l4 * 128 + m) * 8];
        al[rb] = *(const bf16x8*)&Al[(l4 * 128 + m) * 8];
      }
      #pragma unroll
      for (int cb = 0; cb < 4; ++cb) {
        const int nn = wn * 64 + cb * 16 + l15;
        bh[cb] = *(const bf16x8*)&Bh[(l4 * 128 + nn) * 8];
        bl[cb] = *(const bf16x8*)&Bl[(l4 * 128 + nn) * 8];
      }
      #pragma unroll
      for (int rb = 0; rb < 4; ++rb)
        #pragma unroll
        for (int cb = 0; cb < 4; ++cb) {
          acc[rb][cb] = __builtin_amdgcn_mfma_f32_16x16x32_bf16(
              ah[rb], bh[cb], acc[rb][cb], 0, 0, 0);
          acc[rb][cb] = __builtin_amdgcn_mfma_f32_16x16x32_bf16(
              ah[rb], bl[cb], acc[rb][cb], 0, 0, 0);
          acc[rb][cb] = __builtin_amdgcn_mfma_f32_16x16x32_bf16(
              al[rb], bh[cb], acc[rb][cb], 0, 0, 0);
        }
      __syncthreads();
    }

    #pragma unroll
    for (int cb = 0; cb < 4; ++cb) {
      const int col = k0 + kt + wn * 64 + cb * 16 + l15;
      const float wv = wsq[col];
      #pragma unroll
      for (int rb = 0; rb < 4; ++rb) {
        f32x4 a = acc[rb][cb];
        #pragma unroll
        for (int rg = 0; rg < 4; ++rg) {
          const float dist = (zzr[rb * 4 + rg] + wv) - 2.0f * a[rg];
          const int s = rb * 4 + rg;
          if (dist < best[s]) { best[s] = dist; bidx[s] = col; }
        }
      }
    }
  }

  #pragma unroll
  for (int rb = 0; rb < 4; ++rb)
    #pragma unroll
    for (int rg = 0; rg < 4; ++rg) {
      const int s = rb * 4 + rg;
      const int R = wm * 64 + rb * 16 + l4 * 4 + rg;
      rv[R * 32 + wn * 16 + l15] = best[s];
      ri[R * 32 + wn * 16 + l15] = bidx[s];
    }
  __syncthreads();

  if (tid < BMT && rt * BMT + tid < n) {
    float bv = INFINITY;
    int bi = 0x7fffffff;
    #pragma unroll
    for (int t = 0; t < 32; ++t) {
      const float v = rv[tid * 32 + t];
      const int ix = ri[tid * 32 + t];
      if (v < bv || (v == bv && ix < bi)) { bv = v; bi = ix; }
    }
    const int row = list[rt * BMT + tid];
    const unsigned long long pk =
        ((unsigned long long)__float_as_uint(bv) << 32) | (unsigned)bi;
    atomicMin(&packed[row], pk);
  }
}

// ---------------------------------------------------------------------------
// Commit refined rows: unpack, write idx, histogram.
// ---------------------------------------------------------------------------
__global__ __launch_bounds__(256) void final_merge_kernel(
    const int* __restrict__ cnt, const int* __restrict__ list,
    const unsigned long long* __restrict__ packed, int* __restrict__ idx,
    float* __restrict__ out_idx_f, int* __restrict__ hist) {
  const int t = blockIdx.x * 256 + threadIdx.x;
  if (t >= *cnt) return;
  const int row = list[t];
  const int bi = (int)(packed[row] & 0xffffffffULL);
  idx[row] = bi;
  out_idx_f[row] = (float)bi;
  atomicAdd(&hist[bi], 1);
}

// ---------------------------------------------------------------------------
// Gather W[idx], straight-through output, MSE accumulation.
// ---------------------------------------------------------------------------
__global__ __launch_bounds__(256) void gather_kernel(
    const float* __restrict__ z, const float* __restrict__ W,
    const int* __restrict__ idx, float* __restrict__ out,
    double* __restrict__ mse_sum) {
  const int wave = threadIdx.x >> 6;
  const int lane = threadIdx.x & 63;
  const int row = blockIdx.x * 4 + wave;
  const int k = idx[row];
  const float* zr = z + (size_t)row * D_DIM;
  const float* wr = W + (size_t)k * D_DIM;
  float* outr = out + (size_t)row * D_DIM;
  float s = 0.f;
  #pragma unroll
  for (int h = 0; h < 2; ++h) {
    const int c = h * 256 + lane * 4;
    float4 zv = *(const float4*)(zr + c);
    float4 qv = *(const float4*)(wr + c);
    float4 st;
    st.x = zv.x + (qv.x - zv.x);
    st.y = zv.y + (qv.y - zv.y);
    st.z = zv.z + (qv.z - zv.z);
    st.w = zv.w + (qv.w - zv.w);
    float dx = zv.x - qv.x, dy = zv.y - qv.y, dz = zv.z - qv.z, dw = zv.w - qv.w;
    s += dx * dx + dy * dy + dz * dz + dw * dw;
    *(float4*)(outr + c) = st;
  }
  #pragma unroll
  for (int o = 32; o > 0; o >>= 1) s += __shfl_xor(s, o, 64);
  if (lane == 0) atomicAdd(mse_sum, (double)s);
}

// ---------------------------------------------------------------------------
__global__ __launch_bounds__(256) void loss_kernel(
    const int* __restrict__ hist, const double* __restrict__ mse_sum,
    float* __restrict__ out_loss) {
  __shared__ float ls[4];
  const int tid = threadIdx.x;
  float e = 0.f;
  for (int b = tid; b < K_EMB; b += 256) {
    float p = (float)hist[b] * (1.0f / 32768.0f);
    e += p * logf(p + 1e-10f);
  }
  #pragma unroll
  for (int o = 32; o > 0; o >>= 1) e += __shfl_xor(e, o, 64);
  if ((tid & 63) == 0) ls[tid >> 6] = e;
  __syncthreads();
  if (tid == 0) {
    float entropy = -(ls[0] + ls[1] + ls[2] + ls[3]);
    float mse = (float)(*mse_sum / 16777216.0);
    float entropy_loss = 1.0f - entropy / logf(8192.0f);
    out_loss[0] = mse + 0.25f * mse + 0.1f * entropy_loss;
  }
}

// ---------------------------------------------------------------------------
extern "C" void kernel_launch(void* const* d_in, const int* in_sizes, int n_in,
                              void* d_out, int out_size, void* d_ws, size_t ws_size,
                              hipStream_t stream) {
  const float* z = (const float*)d_in[0];  // [32768,512]
  const float* W = (const float*)d_in[1];  // [8192,512]
  float* out = (float*)d_out;              // [B*D] st | [1] loss | [B] indices

  char* ws = (char*)d_ws;
  double* mse_sum = (double*)ws;                           // @0
  int*    cnt     = (int*)(ws + 8);                        // @8
  int*    hist    = (int*)(ws + 4096);                     // 32 KB
  unsigned long long* packed = (unsigned long long*)(ws + 65536);  // 256 KB
  float*  zz   = (float*)(ws + 327680);                    // 128 KB
  float*  wsq  = (float*)(ws + 458752);                    // 32 KB
  int*    idx  = (int*)(ws + 491520);                      // 128 KB
  int*    list = (int*)(ws + 622592);                      // 128 KB
  float*  cv1  = (float*)(ws + 786432);                    // 512 KB
  int*    ci1  = (int*)(ws + 1310720);                     // 512 KB
  float*  cv2  = (float*)(ws + 1835008);                   // 512 KB
  short*  zhi  = (short*)(ws + 4194304);                   // 32 MB
  short*  zlo  = (short*)(ws + 37748736);                  // 32 MB
  short*  whi  = (short*)(ws + 71303168);                  // 8 MB
  short*  wlo  = (short*)(ws + 79691776);                  // 8 MB (ends 84 MB)

  hipMemsetAsync(d_ws, 0, 36864, stream);  // mse_sum + cnt + hist

  prep_kernel<<<B_ROWS / 4, 256, 0, stream>>>(z, zhi, zlo, zz, B_ROWS);
  prep_kernel<<<K_EMB / 4, 256, 0, stream>>>(W, whi, wlo, wsq, K_EMB);

  stage1_kernel<<<(B_ROWS / BMT) * KSPLIT1, 256, 0, stream>>>(
      zhi, whi, wsq, cv1, ci1, cv2);

  merge_flag_kernel<<<B_ROWS / 256, 256, 0, stream>>>(
      cv1, ci1, cv2, idx, out + (size_t)B_ROWS * D_DIM + 1, hist,
      packed, cnt, list);

  refine_kernel<<<(B_ROWS / BMT) * RSPLIT, 256, 0, stream>>>(
      zhi, zlo, whi, wlo, zz, wsq, cnt, list, packed);

  final_merge_kernel<<<B_ROWS / 256, 256, 0, stream>>>(
      cnt, list, packed, idx, out + (size_t)B_ROWS * D_DIM + 1, hist);

  gather_kernel<<<B_ROWS / 4, 256, 0, stream>>>(z, W, idx, out, mse_sum);

  loss_kernel<<<1, 256, 0, stream>>>(hist, mse_sum,
                                     out + (size_t)B_ROWS * D_DIM);
}

// Round 4
// 1266.151 us; speedup vs baseline: 1.4897x; 1.4897x over previous
//
#include <hip/hip_runtime.h>
#include <math.h>

#define B_ROWS 32768
#define D_DIM  512
#define K_EMB  8192

#define BMT 128
#define BNT 128
#define RSPLIT 16
#define KRANGE_R (K_EMB / RSPLIT)   // 512
#define EPS 0.10f

typedef __attribute__((ext_vector_type(4))) float f32x4;
typedef __attribute__((ext_vector_type(8))) short bf16x8;

#define GLL16(gp, lp)                                                          \
  __builtin_amdgcn_global_load_lds(                                            \
      (const __attribute__((address_space(1))) void*)(gp),                     \
      (__attribute__((address_space(3))) void*)(lp), 16, 0, 0)

// ---------------------------------------------------------------------------
// fp32 -> bf16 hi + residual lo (RNE), fused with row squared-norm.
// ---------------------------------------------------------------------------
__device__ __forceinline__ unsigned bf_rne(float x) {
  unsigned u = __float_as_uint(x);
  return (u + 0x7fffu + ((u >> 16) & 1u)) >> 16;
}

__global__ __launch_bounds__(256) void prep_kernel(
    const float* __restrict__ X, short* __restrict__ hi,
    short* __restrict__ lo, float* __restrict__ sq, int nrows) {
  const int wave = threadIdx.x >> 6;
  const int lane = threadIdx.x & 63;
  const int row = blockIdx.x * 4 + wave;
  if (row >= nrows) return;
  const float* xr = X + (size_t)row * D_DIM;
  float4 x0 = ((const float4*)xr)[lane * 2];
  float4 x1 = ((const float4*)xr)[lane * 2 + 1];
  float xs[8] = {x0.x, x0.y, x0.z, x0.w, x1.x, x1.y, x1.z, x1.w};
  union { short s[8]; int4 v; } H, L;
  float ssum = 0.f;
  #pragma unroll
  for (int j = 0; j < 8; ++j) {
    unsigned rh = bf_rne(xs[j]);
    H.s[j] = (short)rh;
    float h = __uint_as_float(rh << 16);
    L.s[j] = (short)bf_rne(xs[j] - h);
    ssum += xs[j] * xs[j];
  }
  *(int4*)(hi + (size_t)row * D_DIM + lane * 8) = H.v;
  *(int4*)(lo + (size_t)row * D_DIM + lane * 8) = L.v;
  #pragma unroll
  for (int o = 32; o > 0; o >>= 1) ssum += __shfl_xor(ssum, o, 64);
  if (lane == 0) sq[row] = ssum;
}

// ---------------------------------------------------------------------------
// Stage 1: persistent-z hi*hi top-2 argmin.
// 256 blocks x 512 threads. z-hi 128-row tile resident in LDS (128 KB,
// [dc64][row128][8] layout), loaded once. Sweep all 8192 codes in 256-code
// k-tiles; per 32-d chunk stage only B (16 KB). 8 waves as 2x4 -> wave tile
// 64 rows x 64 codes. Proxy distance wsq[c] - 2*dot (row-constant zz dropped).
// ---------------------------------------------------------------------------
__global__ __launch_bounds__(512, 2) void stage1_kernel(
    const short* __restrict__ zhi, const short* __restrict__ whi,
    const float* __restrict__ wsq, float* __restrict__ cv1,
    int* __restrict__ ci1, float* __restrict__ cv2) {
  __shared__ short Zt[65536];   // 128 KB: [dc 0..63][row 0..127][8 bf16]
  __shared__ short Bb[8192];    // 16 KB:  [dc 0..3][code 0..255][8 bf16]
  float* rv1 = (float*)Zt;             // post-loop overlay (32 KB)
  int*   ri1 = (int*)(Zt + 16384);     // +32 KB
  float* rv2 = (float*)(Zt + 32768);   // +64 KB

  const int tid = threadIdx.x;
  const int lane = tid & 63;
  const int wave = tid >> 6;     // 0..7
  const int wm = wave >> 2;      // 0..1 : row half
  const int wn = wave & 3;       // 0..3 : code quarter
  const int l15 = lane & 15, l4 = lane >> 4;
  const int row0 = blockIdx.x * 128;

  // one-time z-tile load (slot = dc*128 + row; LDS dest = slot*16 B)
  #pragma unroll
  for (int j = 0; j < 16; ++j) {
    const int slot = j * 512 + tid;
    const int r = slot & 127, dc = slot >> 7;
    GLL16(zhi + (size_t)(row0 + r) * D_DIM + dc * 8, Zt + (size_t)slot * 8);
  }
  __syncthreads();

  float v1[16], v2[16];
  int   i1[16];
  #pragma unroll
  for (int s = 0; s < 16; ++s) { v1[s] = INFINITY; v2[s] = INFINITY; i1[s] = 0x7fffffff; }

  const int bcode = tid & 255;
  const int bdc = tid >> 8;   // 0..1

  for (int kt = 0; kt < K_EMB; kt += 256) {
    f32x4 acc[4][4];
    #pragma unroll
    for (int rb = 0; rb < 4; ++rb)
      #pragma unroll
      for (int cb = 0; cb < 4; ++cb) acc[rb][cb] = (f32x4)0.f;

    for (int d0 = 0; d0 < D_DIM; d0 += 32) {
      GLL16(whi + (size_t)(kt + bcode) * D_DIM + d0 + bdc * 8,
            Bb + (size_t)tid * 8);
      GLL16(whi + (size_t)(kt + bcode) * D_DIM + d0 + (bdc + 2) * 8,
            Bb + (size_t)(tid + 512) * 8);
      __syncthreads();  // drains DMA: B chunk visible

      bf16x8 a[4], b[4];
      const int dcb = d0 >> 3;
      #pragma unroll
      for (int rb = 0; rb < 4; ++rb)
        a[rb] = *(const bf16x8*)&Zt[((dcb + l4) * 128 + wm * 64 + rb * 16 + l15) * 8];
      #pragma unroll
      for (int cb = 0; cb < 4; ++cb)
        b[cb] = *(const bf16x8*)&Bb[(l4 * 256 + wn * 64 + cb * 16 + l15) * 8];
      #pragma unroll
      for (int rb = 0; rb < 4; ++rb)
        #pragma unroll
        for (int cb = 0; cb < 4; ++cb)
          acc[rb][cb] = __builtin_amdgcn_mfma_f32_16x16x32_bf16(
              a[rb], b[cb], acc[rb][cb], 0, 0, 0);
      __syncthreads();  // B reads done before next chunk's DMA overwrites
    }

    // score 256-code tile; C/D layout: col=lane&15, row=(lane>>4)*4+reg
    #pragma unroll
    for (int cb = 0; cb < 4; ++cb) {
      const int col = kt + wn * 64 + cb * 16 + l15;
      const float wv = wsq[col];
      #pragma unroll
      for (int rb = 0; rb < 4; ++rb) {
        f32x4 a = acc[rb][cb];
        #pragma unroll
        for (int rg = 0; rg < 4; ++rg) {
          const float dist = wv - 2.0f * a[rg];
          const int s = rb * 4 + rg;
          if (dist < v1[s] || (dist == v1[s] && col < i1[s])) {
            v2[s] = v1[s]; v1[s] = dist; i1[s] = col;
          } else {
            v2[s] = fminf(v2[s], dist);
          }
        }
      }
    }
  }

  __syncthreads();  // compute done; Zt now dead -> overlay reduction arrays
  #pragma unroll
  for (int rb = 0; rb < 4; ++rb)
    #pragma unroll
    for (int rg = 0; rg < 4; ++rg) {
      const int s = rb * 4 + rg;
      const int R = wm * 64 + rb * 16 + l4 * 4 + rg;
      const int c = wn * 16 + l15;
      rv1[R * 64 + c] = v1[s];
      ri1[R * 64 + c] = i1[s];
      rv2[R * 64 + c] = v2[s];
    }
  __syncthreads();

  if (tid < 128) {
    float V1 = INFINITY, V2 = INFINITY;
    int I1 = 0x7fffffff;
    #pragma unroll 8
    for (int t = 0; t < 64; ++t) {
      const float a1 = rv1[tid * 64 + t];
      const int ai = ri1[tid * 64 + t];
      const float a2 = rv2[tid * 64 + t];
      if (a1 < V1 || (a1 == V1 && ai < I1)) {
        V2 = fminf(V1, a2); V1 = a1; I1 = ai;
      } else {
        V2 = fminf(V2, a1);
      }
    }
    cv1[row0 + tid] = V1; ci1[row0 + tid] = I1; cv2[row0 + tid] = V2;
  }
}

// ---------------------------------------------------------------------------
// Commit unambiguous rows; compact ambiguous rows into refine list.
// ---------------------------------------------------------------------------
__global__ __launch_bounds__(256) void merge_flag_kernel(
    const float* __restrict__ cv1, const int* __restrict__ ci1,
    const float* __restrict__ cv2, int* __restrict__ idx,
    float* __restrict__ out_idx_f, int* __restrict__ hist,
    unsigned long long* __restrict__ packed, int* __restrict__ cnt,
    int* __restrict__ list) {
  const int row = blockIdx.x * 256 + threadIdx.x;
  const float V1 = cv1[row];
  const int I1 = ci1[row];
  const float V2 = cv2[row];
  if (V2 - V1 >= EPS) {
    idx[row] = I1;
    out_idx_f[row] = (float)I1;
    atomicAdd(&hist[I1], 1);
  } else {
    packed[row] = 0xffffffffffffffffULL;
    const int p = atomicAdd(cnt, 1);
    list[p] = row;
  }
}

// ---------------------------------------------------------------------------
// Refine: exact 3-pass distance argmin over ALL codes for flagged rows.
// Split-K=16, merged via packed atomicMin (value-then-lowest-idx order).
// ---------------------------------------------------------------------------
__global__ __launch_bounds__(256, 2) void refine_kernel(
    const short* __restrict__ zhi, const short* __restrict__ zlo,
    const short* __restrict__ whi, const short* __restrict__ wlo,
    const float* __restrict__ zz, const float* __restrict__ wsq,
    const int* __restrict__ cnt, const int* __restrict__ list,
    unsigned long long* __restrict__ packed) {
  __shared__ char smem[32768];
  short* Ah = (short*)smem;
  short* Al = (short*)(smem + 8192);
  short* Bh = (short*)(smem + 16384);
  short* Bl = (short*)(smem + 24576);
  float* rv = (float*)smem;
  int*   ri = (int*)(smem + 16384);

  const int n = *cnt;
  const int bx = blockIdx.x;
  const int rt = bx >> 4;
  const int ks = bx & 15;
  if (rt * BMT >= n) return;
  const int k0 = ks * KRANGE_R;

  const int tid = threadIdx.x;
  const int lane = tid & 63;
  const int wave = tid >> 6;
  const int wm = wave >> 1, wn = wave & 1;
  const int l15 = lane & 15, l4 = lane >> 4;

  const int r0s = tid & 127;
  const int kc0 = tid >> 7;
  const int kc1 = kc0 + 2;
  const int rowg = list[min(rt * BMT + r0s, n - 1)];

  float zzr[16];
  #pragma unroll
  for (int rb = 0; rb < 4; ++rb)
    #pragma unroll
    for (int rg = 0; rg < 4; ++rg) {
      const int m = wm * 64 + rb * 16 + l4 * 4 + rg;
      zzr[rb * 4 + rg] = zz[list[min(rt * BMT + m, n - 1)]];
    }

  float best[16];
  int   bidx[16];
  #pragma unroll
  for (int s = 0; s < 16; ++s) { best[s] = INFINITY; bidx[s] = 0x7fffffff; }

  for (int kt = 0; kt < KRANGE_R; kt += BNT) {
    f32x4 acc[4][4];
    #pragma unroll
    for (int rb = 0; rb < 4; ++rb)
      #pragma unroll
      for (int cb = 0; cb < 4; ++cb) acc[rb][cb] = (f32x4)0.f;

    for (int d0 = 0; d0 < D_DIM; d0 += 32) {
      const size_t ga0 = (size_t)rowg * D_DIM + d0 + kc0 * 8;
      const size_t ga1 = (size_t)rowg * D_DIM + d0 + kc1 * 8;
      const size_t gb0 = (size_t)(k0 + kt + r0s) * D_DIM + d0 + kc0 * 8;
      const size_t gb1 = (size_t)(k0 + kt + r0s) * D_DIM + d0 + kc1 * 8;
      GLL16(zhi + ga0, Ah + (size_t)tid * 8);
      GLL16(zhi + ga1, Ah + (size_t)(tid + 256) * 8);
      GLL16(zlo + ga0, Al + (size_t)tid * 8);
      GLL16(zlo + ga1, Al + (size_t)(tid + 256) * 8);
      GLL16(whi + gb0, Bh + (size_t)tid * 8);
      GLL16(whi + gb1, Bh + (size_t)(tid + 256) * 8);
      GLL16(wlo + gb0, Bl + (size_t)tid * 8);
      GLL16(wlo + gb1, Bl + (size_t)(tid + 256) * 8);
      __syncthreads();

      bf16x8 ah[4], al[4], bh[4], bl[4];
      #pragma unroll
      for (int rb = 0; rb < 4; ++rb) {
        const int m = wm * 64 + rb * 16 + l15;
        ah[rb] = *(const bf16x8*)&Ah[(l4 * 128 + m) * 8];
        al[rb] = *(const bf16x8*)&Al[(l4 * 128 + m) * 8];
      }
      #pragma unroll
      for (int cb = 0; cb < 4; ++cb) {
        const int nn = wn * 64 + cb * 16 + l15;
        bh[cb] = *(const bf16x8*)&Bh[(l4 * 128 + nn) * 8];
        bl[cb] = *(const bf16x8*)&Bl[(l4 * 128 + nn) * 8];
      }
      #pragma unroll
      for (int rb = 0; rb < 4; ++rb)
        #pragma unroll
        for (int cb = 0; cb < 4; ++cb) {
          acc[rb][cb] = __builtin_amdgcn_mfma_f32_16x16x32_bf16(
              ah[rb], bh[cb], acc[rb][cb], 0, 0, 0);
          acc[rb][cb] = __builtin_amdgcn_mfma_f32_16x16x32_bf16(
              ah[rb], bl[cb], acc[rb][cb], 0, 0, 0);
          acc[rb][cb] = __builtin_amdgcn_mfma_f32_16x16x32_bf16(
              al[rb], bh[cb], acc[rb][cb], 0, 0, 0);
        }
      __syncthreads();
    }

    #pragma unroll
    for (int cb = 0; cb < 4; ++cb) {
      const int col = k0 + kt + wn * 64 + cb * 16 + l15;
      const float wv = wsq[col];
      #pragma unroll
      for (int rb = 0; rb < 4; ++rb) {
        f32x4 a = acc[rb][cb];
        #pragma unroll
        for (int rg = 0; rg < 4; ++rg) {
          const float dist = (zzr[rb * 4 + rg] + wv) - 2.0f * a[rg];
          const int s = rb * 4 + rg;
          if (dist < best[s]) { best[s] = dist; bidx[s] = col; }
        }
      }
    }
  }

  #pragma unroll
  for (int rb = 0; rb < 4; ++rb)
    #pragma unroll
    for (int rg = 0; rg < 4; ++rg) {
      const int s = rb * 4 + rg;
      const int R = wm * 64 + rb * 16 + l4 * 4 + rg;
      rv[R * 32 + wn * 16 + l15] = best[s];
      ri[R * 32 + wn * 16 + l15] = bidx[s];
    }
  __syncthreads();

  if (tid < BMT && rt * BMT + tid < n) {
    float bv = INFINITY;
    int bi = 0x7fffffff;
    #pragma unroll
    for (int t = 0; t < 32; ++t) {
      const float v = rv[tid * 32 + t];
      const int ix = ri[tid * 32 + t];
      if (v < bv || (v == bv && ix < bi)) { bv = v; bi = ix; }
    }
    const int row = list[rt * BMT + tid];
    const unsigned long long pk =
        ((unsigned long long)__float_as_uint(bv) << 32) | (unsigned)bi;
    atomicMin(&packed[row], pk);
  }
}

// ---------------------------------------------------------------------------
__global__ __launch_bounds__(256) void final_merge_kernel(
    const int* __restrict__ cnt, const int* __restrict__ list,
    const unsigned long long* __restrict__ packed, int* __restrict__ idx,
    float* __restrict__ out_idx_f, int* __restrict__ hist) {
  const int t = blockIdx.x * 256 + threadIdx.x;
  if (t >= *cnt) return;
  const int row = list[t];
  const int bi = (int)(packed[row] & 0xffffffffULL);
  idx[row] = bi;
  out_idx_f[row] = (float)bi;
  atomicAdd(&hist[bi], 1);
}

// ---------------------------------------------------------------------------
__global__ __launch_bounds__(256) void gather_kernel(
    const float* __restrict__ z, const float* __restrict__ W,
    const int* __restrict__ idx, float* __restrict__ out,
    double* __restrict__ mse_sum) {
  const int wave = threadIdx.x >> 6;
  const int lane = threadIdx.x & 63;
  const int row = blockIdx.x * 4 + wave;
  const int k = idx[row];
  const float* zr = z + (size_t)row * D_DIM;
  const float* wr = W + (size_t)k * D_DIM;
  float* outr = out + (size_t)row * D_DIM;
  float s = 0.f;
  #pragma unroll
  for (int h = 0; h < 2; ++h) {
    const int c = h * 256 + lane * 4;
    float4 zv = *(const float4*)(zr + c);
    float4 qv = *(const float4*)(wr + c);
    float4 st;
    st.x = zv.x + (qv.x - zv.x);
    st.y = zv.y + (qv.y - zv.y);
    st.z = zv.z + (qv.z - zv.z);
    st.w = zv.w + (qv.w - zv.w);
    float dx = zv.x - qv.x, dy = zv.y - qv.y, dz = zv.z - qv.z, dw = zv.w - qv.w;
    s += dx * dx + dy * dy + dz * dz + dw * dw;
    *(float4*)(outr + c) = st;
  }
  #pragma unroll
  for (int o = 32; o > 0; o >>= 1) s += __shfl_xor(s, o, 64);
  if (lane == 0) atomicAdd(mse_sum, (double)s);
}

// ---------------------------------------------------------------------------
__global__ __launch_bounds__(256) void loss_kernel(
    const int* __restrict__ hist, const double* __restrict__ mse_sum,
    float* __restrict__ out_loss) {
  __shared__ float ls[4];
  const int tid = threadIdx.x;
  float e = 0.f;
  for (int b = tid; b < K_EMB; b += 256) {
    float p = (float)hist[b] * (1.0f / 32768.0f);
    e += p * logf(p + 1e-10f);
  }
  #pragma unroll
  for (int o = 32; o > 0; o >>= 1) e += __shfl_xor(e, o, 64);
  if ((tid & 63) == 0) ls[tid >> 6] = e;
  __syncthreads();
  if (tid == 0) {
    float entropy = -(ls[0] + ls[1] + ls[2] + ls[3]);
    float mse = (float)(*mse_sum / 16777216.0);
    float entropy_loss = 1.0f - entropy / logf(8192.0f);
    out_loss[0] = mse + 0.25f * mse + 0.1f * entropy_loss;
  }
}

// ---------------------------------------------------------------------------
extern "C" void kernel_launch(void* const* d_in, const int* in_sizes, int n_in,
                              void* d_out, int out_size, void* d_ws, size_t ws_size,
                              hipStream_t stream) {
  const float* z = (const float*)d_in[0];  // [32768,512]
  const float* W = (const float*)d_in[1];  // [8192,512]
  float* out = (float*)d_out;              // [B*D] st | [1] loss | [B] indices

  char* ws = (char*)d_ws;
  double* mse_sum = (double*)ws;                           // @0
  int*    cnt     = (int*)(ws + 8);                        // @8
  int*    hist    = (int*)(ws + 4096);                     // 32 KB
  unsigned long long* packed = (unsigned long long*)(ws + 65536);  // 256 KB
  float*  zz   = (float*)(ws + 327680);                    // 128 KB
  float*  wsq  = (float*)(ws + 458752);                    // 32 KB
  int*    idx  = (int*)(ws + 491520);                      // 128 KB
  int*    list = (int*)(ws + 622592);                      // 128 KB
  float*  cv1  = (float*)(ws + 786432);                    // [B_ROWS]
  int*    ci1  = (int*)(ws + 1310720);                     // [B_ROWS]
  float*  cv2  = (float*)(ws + 1835008);                   // [B_ROWS]
  short*  zhi  = (short*)(ws + 4194304);                   // 32 MB
  short*  zlo  = (short*)(ws + 37748736);                  // 32 MB
  short*  whi  = (short*)(ws + 71303168);                  // 8 MB
  short*  wlo  = (short*)(ws + 79691776);                  // 8 MB (ends 84 MB)

  hipMemsetAsync(d_ws, 0, 36864, stream);  // mse_sum + cnt + hist

  prep_kernel<<<B_ROWS / 4, 256, 0, stream>>>(z, zhi, zlo, zz, B_ROWS);
  prep_kernel<<<K_EMB / 4, 256, 0, stream>>>(W, whi, wlo, wsq, K_EMB);

  stage1_kernel<<<B_ROWS / 128, 512, 0, stream>>>(zhi, whi, wsq, cv1, ci1, cv2);

  merge_flag_kernel<<<B_ROWS / 256, 256, 0, stream>>>(
      cv1, ci1, cv2, idx, out + (size_t)B_ROWS * D_DIM + 1, hist,
      packed, cnt, list);

  refine_kernel<<<(B_ROWS / BMT) * RSPLIT, 256, 0, stream>>>(
      zhi, zlo, whi, wlo, zz, wsq, cnt, list, packed);

  final_merge_kernel<<<B_ROWS / 256, 256, 0, stream>>>(
      cnt, list, packed, idx, out + (size_t)B_ROWS * D_DIM + 1, hist);

  gather_kernel<<<B_ROWS / 4, 256, 0, stream>>>(z, W, idx, out, mse_sum);

  loss_kernel<<<1, 256, 0, stream>>>(hist, mse_sum,
                                     out + (size_t)B_ROWS * D_DIM);
}